// Round 3
// baseline (345.666 us; speedup 1.0000x reference)
//
#include <hip/hip_runtime.h>

#define WPB 4            // waves per block
#define BT  256          // block threads
#define G   4            // points per wave-iteration
#define MAXN 4           // max batch count supported
#define RED_THREADS 512

// Persistent-wave streaming kernel. Each wave owns a contiguous range of
// points and iterates over them G at a time:
//   prologue: global->reg loads for chunk 0
//   loop:     regs->LDS, prefetch chunk i+1 into regs (overlaps), compute
// Per iteration each thread issues 7 independent dwordx4 loads (v:3, vn:3,
// sr:1) -> deep MLP; wave launch cost amortized over ~10 iterations; atomics
// reduced to <=2 per wave (accumulated in registers).
__global__ __launch_bounds__(BT) void sdf_main(
    const float* __restrict__ points,
    const float* __restrict__ v,
    const float* __restrict__ vn,
    const float* __restrict__ sr,
    float* __restrict__ ws,
    int NP, int P, int cpw, int iters, int slots, int slotStride)
{
    constexpr int K   = 60;
    constexpr int VF4 = 45;   // float4 per point in v / vn rows
    constexpr int SF4 = 15;   // float4 per point in sr row
    // per-wave region: [v: G*45 | vn: G*45 | sr: G*15] float4 = 420 f4 = 6720 B
    __shared__ float4 buf[WPB][G * (2 * VF4 + SF4)];

    const int w      = threadIdx.x >> 6;
    const int lane   = threadIdx.x & 63;
    const int waveId = blockIdx.x * WPB + w;
    const int p0     = waveId * cpw;
    const int pEnd   = min(NP, p0 + cpw);

    float4* lv = &buf[w][0];
    float4* ln = &buf[w][G * VF4];
    float4* ls = &buf[w][2 * G * VF4];

    float acc[MAXN];
    #pragma unroll
    for (int i = 0; i < MAXN; ++i) acc[i] = 0.f;

    float4 z = {0.f, 0.f, 0.f, 0.f};
    float4 rv0 = z, rv1 = z, rv2 = z, rn0 = z, rn1 = z, rn2 = z, rs0 = z;

    // prologue: load chunk 0
    {
        const int npts = max(0, min(G, pEnd - p0));
        const int nv = npts * VF4, ns = npts * SF4;
        const float4* v4 = (const float4*)(v  + (size_t)p0 * (K * 3));
        const float4* n4 = (const float4*)(vn + (size_t)p0 * (K * 3));
        const float4* s4 = (const float4*)(sr + (size_t)p0 * K);
        if (lane       < nv) rv0 = v4[lane];
        if (lane +  64 < nv) rv1 = v4[lane + 64];
        if (lane + 128 < nv) rv2 = v4[lane + 128];
        if (lane       < nv) rn0 = n4[lane];
        if (lane +  64 < nv) rn1 = n4[lane + 64];
        if (lane + 128 < nv) rn2 = n4[lane + 128];
        if (lane       < ns) rs0 = s4[lane];
    }

    for (int it = 0; it < iters; ++it) {
        const int p    = p0 + it * G;
        const int npts = max(0, min(G, pEnd - p));
        const int nv = npts * VF4, ns = npts * SF4;

        __syncthreads();   // prior iteration's LDS reads complete
        if (lane       < nv) lv[lane      ] = rv0;
        if (lane +  64 < nv) lv[lane +  64] = rv1;
        if (lane + 128 < nv) lv[lane + 128] = rv2;
        if (lane       < nv) ln[lane      ] = rn0;
        if (lane +  64 < nv) ln[lane +  64] = rn1;
        if (lane + 128 < nv) ln[lane + 128] = rn2;
        if (lane       < ns) ls[lane      ] = rs0;
        __syncthreads();   // writes visible

        // prefetch chunk it+1 while computing chunk it
        {
            const int pn = p + G;
            const int nn = max(0, min(G, pEnd - pn));
            const int nv2 = nn * VF4, ns2 = nn * SF4;
            const float4* v4 = (const float4*)(v  + (size_t)pn * (K * 3));
            const float4* n4 = (const float4*)(vn + (size_t)pn * (K * 3));
            const float4* s4 = (const float4*)(sr + (size_t)pn * K);
            if (lane       < nv2) rv0 = v4[lane];
            if (lane +  64 < nv2) rv1 = v4[lane + 64];
            if (lane + 128 < nv2) rv2 = v4[lane + 128];
            if (lane       < nv2) rn0 = n4[lane];
            if (lane +  64 < nv2) rn1 = n4[lane + 64];
            if (lane + 128 < nv2) rn2 = n4[lane + 128];
            if (lane       < ns2) rs0 = s4[lane];
        }

        const float* vf = (const float*)lv;
        const float* nf = (const float*)ln;
        const float* sf = (const float*)ls;

        #pragma unroll
        for (int g = 0; g < G; ++g) {
            float num = 0.f, den = 0.f;
            if (g < npts && lane < K) {
                const int pt = p + g;
                const float px = points[pt * 3 + 0];
                const float py = points[pt * 3 + 1];
                const float pz = points[pt * 3 + 2];
                const float vx = vf[g * (VF4 * 4) + 3 * lane + 0];
                const float vy = vf[g * (VF4 * 4) + 3 * lane + 1];
                const float vz = vf[g * (VF4 * 4) + 3 * lane + 2];
                const float nx = nf[g * (VF4 * 4) + 3 * lane + 0];
                const float ny = nf[g * (VF4 * 4) + 3 * lane + 1];
                const float nz = nf[g * (VF4 * 4) + 3 * lane + 2];
                const float s  = sf[g * (SF4 * 4) + lane];

                const float dx = px - vx;
                const float dy = py - vy;
                const float dz = pz - vz;
                const float d2 = dx * dx + dy * dy + dz * dz;
                const float wq = 1.0f - d2 / s;
                const float w2 = wq * wq;
                const float phi = (d2 < s) ? (w2 * w2) : 1e-18f;
                const float dot = nx * dx + ny * dy + nz * dz;
                num = phi * dot;
                den = phi;
            }
            #pragma unroll
            for (int off = 32; off >= 1; off >>= 1) {
                num += __shfl_xor(num, off, 64);
                den += __shfl_xor(den, off, 64);
            }
            if (lane == 0 && g < npts) {
                const float sdf = num / den;
                const int n = (p + g) / P;
                if (n < MAXN) acc[n] += sdf * sdf;
            }
        }
    }

    if (lane == 0) {
        const int slot = waveId & (slots - 1);
        #pragma unroll
        for (int n = 0; n < MAXN; ++n)
            if (acc[n] != 0.f) atomicAdd(&ws[slot * slotStride + n], acc[n]);
    }
}

// Single-block final reduction over `slots` partial sums per batch index.
__global__ __launch_bounds__(RED_THREADS) void sdf_reduce(
    const float* __restrict__ ws, float* __restrict__ out,
    int N, int slots, int slotStride)
{
    __shared__ float sm0[RED_THREADS];
    __shared__ float sm1[RED_THREADS];
    const int tid = threadIdx.x;
    float a = 0.f, b = 0.f;
    for (int s = tid; s < slots; s += RED_THREADS) {
        a += ws[s * slotStride + 0];
        if (N > 1) b += ws[s * slotStride + 1];
    }
    sm0[tid] = a;
    sm1[tid] = b;
    __syncthreads();
    #pragma unroll
    for (int s = RED_THREADS / 2; s >= 1; s >>= 1) {
        if (tid < s) {
            sm0[tid] += sm0[tid + s];
            sm1[tid] += sm1[tid + s];
        }
        __syncthreads();
    }
    if (tid == 0) {
        out[0] = sm0[0];
        if (N > 1) out[1] = sm1[0];
    }
}

extern "C" void kernel_launch(void* const* d_in, const int* in_sizes, int n_in,
                              void* d_out, int out_size, void* d_ws, size_t ws_size,
                              hipStream_t stream) {
    const float* points = (const float*)d_in[0];
    const float* v      = (const float*)d_in[1];
    const float* vn     = (const float*)d_in[2];
    const float* sr     = (const float*)d_in[3];
    float* out = (float*)d_out;
    float* ws  = (float*)d_ws;

    const int NP = in_sizes[0] / 3;        // N*P total points (200000)
    const int N  = out_size;               // 2
    const int P  = NP / N;                 // 100000

    int slots = 512, slotStride = 16;      // one 64-B line per slot
    if (ws_size < (size_t)(slots * slotStride * sizeof(float))) {
        slots = 256; slotStride = 2;
    }

    hipMemsetAsync(ws, 0, (size_t)slots * slotStride * sizeof(float), stream);

    const int blocks = 1280;               // 5 blocks/CU (LDS: 26.9 KB/block)
    const int waves  = blocks * WPB;       // 5120 waves
    const int cpw    = (NP + waves - 1) / waves;   // points per wave (40)
    const int iters  = (cpw + G - 1) / G;          // uniform across grid (10)

    sdf_main<<<blocks, BT, 0, stream>>>(points, v, vn, sr, ws,
                                        NP, P, cpw, iters, slots, slotStride);
    sdf_reduce<<<1, RED_THREADS, 0, stream>>>(ws, out, N, slots, slotStride);
}

// Round 4
// 333.605 us; speedup vs baseline: 1.0362x; 1.0362x over previous
//
#include <hip/hip_runtime.h>

#define BT  256
#define WPB (BT / 64)
#define RED_THREADS 512
#define EPS_PHI 1e-18f

// Fast path: K == 60, NP % 4 == 0.
// 16 lanes per point, 4 points per wave. Lane t covers neighbors
// k = t, t+16, t+32, t+48 (k=48+t clamped to 59 / zeroed for t>=12).
// All loads are direct global->register: per 16-lane group each v/vn
// access is a contiguous 192-B run (merged dwordx3), sr is one 64-B line.
// No LDS staging, no barriers; per-point reduction is a 4-step butterfly
// amortized over 4 points (2 DS ops/point vs ~26 in the previous design).
__global__ __launch_bounds__(BT, 4) void sdf_main60(
    const float* __restrict__ points,
    const float* __restrict__ v,
    const float* __restrict__ vn,
    const float* __restrict__ sr,
    float* __restrict__ ws,
    int P, int nGroups, int nWaves, int slots, int slotStride)
{
    const int lane   = threadIdx.x & 63;
    const int waveId = blockIdx.x * WPB + (threadIdx.x >> 6);
    const int t = lane & 15;   // neighbor slot within point
    const int g = lane >> 4;   // point within group

    // clamped indices for the c=3 pass (k = 48 + t, valid only t < 12)
    const int  i3     = (t < 12) ? (144 + 3 * t) : 177;  // float idx in v/vn row
    const int  s3i    = (t < 12) ? (48 + t)      : 59;   // idx in sr row
    const bool valid3 = (t < 12);

    float acc0 = 0.f, acc1 = 0.f;

    for (int grp = waveId; grp < nGroups; grp += nWaves) {
        const int p = grp * 4 + g;
        const float* __restrict__ vrow = v      + (size_t)p * 180;
        const float* __restrict__ nrow = vn     + (size_t)p * 180;
        const float* __restrict__ srow = sr     + (size_t)p * 60;
        const float* __restrict__ prow = points + (size_t)p * 3;
        const int i0 = 3 * t;

        // ---- issue all independent loads up front (13 wide loads/lane) ----
        const float vx0 = vrow[i0 +  0], vy0 = vrow[i0 +  1], vz0 = vrow[i0 +  2];
        const float vx1 = vrow[i0 + 48], vy1 = vrow[i0 + 49], vz1 = vrow[i0 + 50];
        const float vx2 = vrow[i0 + 96], vy2 = vrow[i0 + 97], vz2 = vrow[i0 + 98];
        const float vx3 = vrow[i3 +  0], vy3 = vrow[i3 +  1], vz3 = vrow[i3 +  2];
        const float nx0 = nrow[i0 +  0], ny0 = nrow[i0 +  1], nz0 = nrow[i0 +  2];
        const float nx1 = nrow[i0 + 48], ny1 = nrow[i0 + 49], nz1 = nrow[i0 + 50];
        const float nx2 = nrow[i0 + 96], ny2 = nrow[i0 + 97], nz2 = nrow[i0 + 98];
        const float nx3 = nrow[i3 +  0], ny3 = nrow[i3 +  1], nz3 = nrow[i3 +  2];
        const float s0 = srow[t], s1 = srow[t + 16], s2 = srow[t + 32], s3 = srow[s3i];
        const float px = prow[0], py = prow[1], pz = prow[2];

        float num = 0.f, den = 0.f;
        auto body = [&](float vx, float vy, float vz,
                        float nx, float ny, float nz,
                        float s, bool valid) {
            const float dx = px - vx, dy = py - vy, dz = pz - vz;
            const float d2 = dx * dx + dy * dy + dz * dz;
            const float rs = __builtin_amdgcn_rcpf(s);
            const float w  = 1.f - d2 * rs;
            const float w2 = w * w;
            float phi = (d2 < s) ? (w2 * w2) : EPS_PHI;
            if (!valid) phi = 0.f;
            const float dot = nx * dx + ny * dy + nz * dz;
            num += phi * dot;
            den += phi;
        };
        body(vx0, vy0, vz0, nx0, ny0, nz0, s0, true);
        body(vx1, vy1, vz1, nx1, ny1, nz1, s1, true);
        body(vx2, vy2, vz2, nx2, ny2, nz2, s2, true);
        body(vx3, vy3, vz3, nx3, ny3, nz3, s3, valid3);

        // ---- 16-lane butterfly (covers 4 points at once): 8 DS ops ----
        #pragma unroll
        for (int off = 1; off <= 8; off <<= 1) {
            num += __shfl_xor(num, off, 64);
            den += __shfl_xor(den, off, 64);
        }

        const float sdf = num * __builtin_amdgcn_rcpf(den);
        const float sq  = sdf * sdf;
        if (t == 0) {
            if (p < P) acc0 += sq; else acc1 += sq;
        }
    }

    // wave-wide final reduction, once per wave lifetime
    #pragma unroll
    for (int off = 1; off <= 32; off <<= 1) {
        acc0 += __shfl_xor(acc0, off, 64);
        acc1 += __shfl_xor(acc1, off, 64);
    }
    if (lane == 0) {
        const int slot = waveId & (slots - 1);
        atomicAdd(&ws[slot * slotStride + 0], acc0);
        atomicAdd(&ws[slot * slotStride + 1], acc1);
    }
}

// Generic fallback (any K / NP): one thread per point, correctness-first.
__global__ void sdf_generic(
    const float* __restrict__ points,
    const float* __restrict__ v,
    const float* __restrict__ vn,
    const float* __restrict__ sr,
    float* __restrict__ ws,
    int NP, int P, int K, int slots, int slotStride)
{
    const int p = blockIdx.x * blockDim.x + threadIdx.x;
    if (p >= NP) return;
    const float px = points[p * 3 + 0];
    const float py = points[p * 3 + 1];
    const float pz = points[p * 3 + 2];
    float num = 0.f, den = 0.f;
    for (int k = 0; k < K; ++k) {
        const size_t b = ((size_t)p * K + k) * 3;
        const float dx = px - v[b + 0];
        const float dy = py - v[b + 1];
        const float dz = pz - v[b + 2];
        const float d2 = dx * dx + dy * dy + dz * dz;
        const float s  = sr[(size_t)p * K + k];
        const float w  = 1.f - d2 / s;
        const float w2 = w * w;
        const float phi = (d2 < s) ? (w2 * w2) : EPS_PHI;
        const float dot = vn[b + 0] * dx + vn[b + 1] * dy + vn[b + 2] * dz;
        num += phi * dot;
        den += phi;
    }
    const float sdf = num / den;
    const int n = p / P;
    const int slot = p & (slots - 1);
    if (n < slotStride) atomicAdd(&ws[slot * slotStride + n], sdf * sdf);
}

// Single-block final reduction over `slots` partial sums per batch index.
__global__ __launch_bounds__(RED_THREADS) void sdf_reduce(
    const float* __restrict__ ws, float* __restrict__ out,
    int N, int slots, int slotStride)
{
    __shared__ float sm0[RED_THREADS];
    __shared__ float sm1[RED_THREADS];
    const int tid = threadIdx.x;
    float a = 0.f, b = 0.f;
    for (int s = tid; s < slots; s += RED_THREADS) {
        a += ws[s * slotStride + 0];
        if (N > 1) b += ws[s * slotStride + 1];
    }
    sm0[tid] = a;
    sm1[tid] = b;
    __syncthreads();
    #pragma unroll
    for (int s = RED_THREADS / 2; s >= 1; s >>= 1) {
        if (tid < s) {
            sm0[tid] += sm0[tid + s];
            sm1[tid] += sm1[tid + s];
        }
        __syncthreads();
    }
    if (tid == 0) {
        out[0] = sm0[0];
        if (N > 1) out[1] = sm1[0];
    }
}

extern "C" void kernel_launch(void* const* d_in, const int* in_sizes, int n_in,
                              void* d_out, int out_size, void* d_ws, size_t ws_size,
                              hipStream_t stream) {
    const float* points = (const float*)d_in[0];
    const float* v      = (const float*)d_in[1];
    const float* vn     = (const float*)d_in[2];
    const float* sr     = (const float*)d_in[3];
    float* out = (float*)d_out;
    float* ws  = (float*)d_ws;

    const int NP = in_sizes[0] / 3;        // N*P total points (200000)
    const int K  = in_sizes[3] / NP;       // 60
    const int N  = out_size;               // 2
    const int P  = NP / N;                 // 100000

    int slots = 512, slotStride = 16;      // one 64-B line per slot
    if (ws_size < (size_t)(slots * slotStride * sizeof(float))) {
        slots = 256; slotStride = 2;
    }

    hipMemsetAsync(ws, 0, (size_t)slots * slotStride * sizeof(float), stream);

    if (K == 60 && (NP & 3) == 0) {
        const int blocks  = 2048;                  // 8 blocks/CU worth of work
        const int nWaves  = blocks * WPB;          // 8192 waves
        const int nGroups = NP / 4;                // 50000 groups of 4 points
        sdf_main60<<<blocks, BT, 0, stream>>>(points, v, vn, sr, ws,
                                              P, nGroups, nWaves,
                                              slots, slotStride);
    } else {
        sdf_generic<<<(NP + BT - 1) / BT, BT, 0, stream>>>(
            points, v, vn, sr, ws, NP, P, K, slots, slotStride);
    }
    sdf_reduce<<<1, RED_THREADS, 0, stream>>>(ws, out, N, slots, slotStride);
}

// Round 5
// 333.299 us; speedup vs baseline: 1.0371x; 1.0009x over previous
//
#include <hip/hip_runtime.h>

#define BT  256
#define WPB (BT / 64)
#define RED_THREADS 512
#define EPS_PHI 1e-18f

// Fast path: K == 60, NP % 8 == 0.
// Mapping: 16 lanes per point, 4 points per 64-lane group, TWO 4-point groups
// per iteration (8 points). Lane chunk t in [0,15) owns neighbors 4t..4t+3,
// whose coords are floats 12t..12t+11 = exactly 3 aligned float4s of the
// 720-B v row (and vn row); its 4 sr values are 1 aligned float4. All 14
// float4 loads of an iteration are issued into explicit float4 registers
// BEFORE any use -> compiler cannot narrow or serialize them; ~14 KB in
// flight per wave closes the Little's-law gap that capped R4 at 4.6 B/cyc/CU.
// t == 15 is masked (clamped load indices, zeroed contribution).
__global__ __launch_bounds__(BT, 4) void sdf_main60(
    const float* __restrict__ points,
    const float* __restrict__ v,
    const float* __restrict__ vn,
    const float* __restrict__ sr,
    float* __restrict__ ws,
    int P, int nPairs, int nWaves, int slots, int slotStride)
{
    const int lane   = threadIdx.x & 63;
    const int waveId = blockIdx.x * WPB + (threadIdx.x >> 6);
    const int g  = lane >> 4;            // point within group (0..3)
    const int t  = lane & 15;            // neighbor-chunk within point
    const int tc = (t < 15) ? t : 14;    // clamped chunk index for loads
    const bool act = (t < 15);

    float acc0 = 0.f, acc1 = 0.f;

    for (int pr = waveId; pr < nPairs; pr += nWaves) {
        const int pA = pr * 8 + g;       // group-A point
        const int pB = pA + 4;           // group-B point

        const float4* vA = (const float4*)(v  + (size_t)pA * 180);
        const float4* nA = (const float4*)(vn + (size_t)pA * 180);
        const float4* sA = (const float4*)(sr + (size_t)pA * 60);
        const float4* vB = (const float4*)(v  + (size_t)pB * 180);
        const float4* nB = (const float4*)(vn + (size_t)pB * 180);
        const float4* sB = (const float4*)(sr + (size_t)pB * 60);

        // ---- issue ALL loads of the iteration up front (14 dwordx4/lane) ----
        const float4 av0 = vA[3 * tc + 0], av1 = vA[3 * tc + 1], av2 = vA[3 * tc + 2];
        const float4 an0 = nA[3 * tc + 0], an1 = nA[3 * tc + 1], an2 = nA[3 * tc + 2];
        const float4 as4 = sA[tc];
        const float4 bv0 = vB[3 * tc + 0], bv1 = vB[3 * tc + 1], bv2 = vB[3 * tc + 2];
        const float4 bn0 = nB[3 * tc + 0], bn1 = nB[3 * tc + 1], bn2 = nB[3 * tc + 2];
        const float4 bs4 = sB[tc];
        const float pxA = points[pA * 3 + 0], pyA = points[pA * 3 + 1], pzA = points[pA * 3 + 2];
        const float pxB = points[pB * 3 + 0], pyB = points[pB * 3 + 1], pzB = points[pB * 3 + 2];

        auto quad = [&](const float4& c0, const float4& c1, const float4& c2,
                        const float4& m0, const float4& m1, const float4& m2,
                        const float4& s4, float px, float py, float pz,
                        float& num, float& den) {
            auto one = [&](float vx, float vy, float vz,
                           float nx, float ny, float nz, float s) {
                const float dx = px - vx, dy = py - vy, dz = pz - vz;
                const float d2 = dx * dx + dy * dy + dz * dz;
                const float w  = 1.f - d2 * __builtin_amdgcn_rcpf(s);
                const float w2 = w * w;
                float phi = (d2 < s) ? (w2 * w2) : EPS_PHI;
                if (!act) phi = 0.f;
                num += phi * (nx * dx + ny * dy + nz * dz);
                den += phi;
            };
            one(c0.x, c0.y, c0.z, m0.x, m0.y, m0.z, s4.x);
            one(c0.w, c1.x, c1.y, m0.w, m1.x, m1.y, s4.y);
            one(c1.z, c1.w, c2.x, m1.z, m1.w, m2.x, s4.z);
            one(c2.y, c2.z, c2.w, m2.y, m2.z, m2.w, s4.w);
        };

        float numA = 0.f, denA = 0.f, numB = 0.f, denB = 0.f;
        quad(av0, av1, av2, an0, an1, an2, as4, pxA, pyA, pzA, numA, denA);
        quad(bv0, bv1, bv2, bn0, bn1, bn2, bs4, pxB, pyB, pzB, numB, denB);

        // ---- 16-lane butterfly: reduces 8 points with 16 DS ops ----
        #pragma unroll
        for (int off = 1; off <= 8; off <<= 1) {
            numA += __shfl_xor(numA, off, 64);
            denA += __shfl_xor(denA, off, 64);
            numB += __shfl_xor(numB, off, 64);
            denB += __shfl_xor(denB, off, 64);
        }

        if (t == 0) {
            const float sdfA = numA * __builtin_amdgcn_rcpf(denA);
            const float sdfB = numB * __builtin_amdgcn_rcpf(denB);
            const float sqA = sdfA * sdfA, sqB = sdfB * sdfB;
            if (pA < P) acc0 += sqA; else acc1 += sqA;
            if (pB < P) acc0 += sqB; else acc1 += sqB;
        }
    }

    // wave-wide final reduction, once per wave lifetime
    #pragma unroll
    for (int off = 1; off <= 32; off <<= 1) {
        acc0 += __shfl_xor(acc0, off, 64);
        acc1 += __shfl_xor(acc1, off, 64);
    }
    if (lane == 0) {
        const int slot = waveId & (slots - 1);
        atomicAdd(&ws[slot * slotStride + 0], acc0);
        atomicAdd(&ws[slot * slotStride + 1], acc1);
    }
}

// Generic fallback (any K / NP): one thread per point, correctness-first.
__global__ void sdf_generic(
    const float* __restrict__ points,
    const float* __restrict__ v,
    const float* __restrict__ vn,
    const float* __restrict__ sr,
    float* __restrict__ ws,
    int NP, int P, int K, int slots, int slotStride)
{
    const int p = blockIdx.x * blockDim.x + threadIdx.x;
    if (p >= NP) return;
    const float px = points[p * 3 + 0];
    const float py = points[p * 3 + 1];
    const float pz = points[p * 3 + 2];
    float num = 0.f, den = 0.f;
    for (int k = 0; k < K; ++k) {
        const size_t b = ((size_t)p * K + k) * 3;
        const float dx = px - v[b + 0];
        const float dy = py - v[b + 1];
        const float dz = pz - v[b + 2];
        const float d2 = dx * dx + dy * dy + dz * dz;
        const float s  = sr[(size_t)p * K + k];
        const float w  = 1.f - d2 / s;
        const float w2 = w * w;
        const float phi = (d2 < s) ? (w2 * w2) : EPS_PHI;
        const float dot = vn[b + 0] * dx + vn[b + 1] * dy + vn[b + 2] * dz;
        num += phi * dot;
        den += phi;
    }
    const float sdf = num / den;
    const int n = p / P;
    const int slot = p & (slots - 1);
    if (n < slotStride) atomicAdd(&ws[slot * slotStride + n], sdf * sdf);
}

// Single-block final reduction over `slots` partial sums per batch index.
__global__ __launch_bounds__(RED_THREADS) void sdf_reduce(
    const float* __restrict__ ws, float* __restrict__ out,
    int N, int slots, int slotStride)
{
    __shared__ float sm0[RED_THREADS];
    __shared__ float sm1[RED_THREADS];
    const int tid = threadIdx.x;
    float a = 0.f, b = 0.f;
    for (int s = tid; s < slots; s += RED_THREADS) {
        a += ws[s * slotStride + 0];
        if (N > 1) b += ws[s * slotStride + 1];
    }
    sm0[tid] = a;
    sm1[tid] = b;
    __syncthreads();
    #pragma unroll
    for (int s = RED_THREADS / 2; s >= 1; s >>= 1) {
        if (tid < s) {
            sm0[tid] += sm0[tid + s];
            sm1[tid] += sm1[tid + s];
        }
        __syncthreads();
    }
    if (tid == 0) {
        out[0] = sm0[0];
        if (N > 1) out[1] = sm1[0];
    }
}

extern "C" void kernel_launch(void* const* d_in, const int* in_sizes, int n_in,
                              void* d_out, int out_size, void* d_ws, size_t ws_size,
                              hipStream_t stream) {
    const float* points = (const float*)d_in[0];
    const float* v      = (const float*)d_in[1];
    const float* vn     = (const float*)d_in[2];
    const float* sr     = (const float*)d_in[3];
    float* out = (float*)d_out;
    float* ws  = (float*)d_ws;

    const int NP = in_sizes[0] / 3;        // N*P total points (200000)
    const int K  = in_sizes[3] / NP;       // 60
    const int N  = out_size;               // 2
    const int P  = NP / N;                 // 100000

    int slots = 512, slotStride = 16;      // one 64-B line per slot
    if (ws_size < (size_t)(slots * slotStride * sizeof(float))) {
        slots = 256; slotStride = 2;
    }

    hipMemsetAsync(ws, 0, (size_t)slots * slotStride * sizeof(float), stream);

    if (K == 60 && (NP & 7) == 0) {
        const int blocks = 2048;
        const int nWaves = blocks * WPB;   // 8192 waves
        const int nPairs = NP / 8;         // 25000 iterations of 8 points
        sdf_main60<<<blocks, BT, 0, stream>>>(points, v, vn, sr, ws,
                                              P, nPairs, nWaves,
                                              slots, slotStride);
    } else {
        sdf_generic<<<(NP + BT - 1) / BT, BT, 0, stream>>>(
            points, v, vn, sr, ws, NP, P, K, slots, slotStride);
    }
    sdf_reduce<<<1, RED_THREADS, 0, stream>>>(ws, out, N, slots, slotStride);
}

// Round 6
// 330.679 us; speedup vs baseline: 1.0453x; 1.0079x over previous
//
#include <hip/hip_runtime.h>

#define BT  128              // 2 waves per block
#define WPB 2
#define RED_THREADS 512
#define EPS_PHI 1e-18f

// Address-space helpers for the global->LDS DMA builtin.
#define AS1 __attribute__((address_space(1)))
#define AS3 __attribute__((address_space(3)))
#define GLDS(gp, lp) __builtin_amdgcn_global_load_lds( \
    (const AS1 void*)(gp), (AS3 void*)(lp), 16, 0, 0)

// Fast path: K == 60, NP % 4 == 0.
// Per-wave-private LDS ring (3 statically distinct buffers, so the compiler's
// per-object LDS-DMA alias tracking can order ds_read against only the
// matching buffer's DMA). Chunk = 4 points: v rows (2880 B) + vn rows (2880 B)
// staged by 6 wave-contiguous 1024-B global_load_lds instructions (parts at
// byte offsets 0 / 1024 / 1856, the last overlapping-but-identical). sr and
// point coords ride a 2-deep register pipeline. NO __syncthreads anywhere.
// Compute mapping: 16 lanes per point, lane t<15 owns neighbors 4t..4t+3
// (3 float4 of v, 3 of vn, 1 of sr); t==15 masked.
__global__ __launch_bounds__(BT) void sdf_main60(
    const float* __restrict__ points,
    const float* __restrict__ v,
    const float* __restrict__ vn,
    const float* __restrict__ sr,
    float* __restrict__ ws,
    int P, int nGroups, int nWaves, int T, int slots, int slotStride)
{
    __shared__ float4 b0[WPB][360];   // [v:180 f4 | vn:180 f4] per wave
    __shared__ float4 b1[WPB][360];
    __shared__ float4 b2[WPB][360];

    const int lane   = threadIdx.x & 63;
    const int w      = threadIdx.x >> 6;
    const int waveId = blockIdx.x * WPB + w;
    const int g  = lane >> 4;            // point within chunk (0..3)
    const int t  = lane & 15;            // neighbor-chunk within point
    const int tc = (t < 15) ? t : 14;    // clamped for loads
    const bool act = (t < 15);

    float acc0 = 0.f, acc1 = 0.f;

    // async DMA of chunk grp (4 points of v & vn) into wave-private buffer lb
    auto issue = [&](int grp, float4* lb) {
        const float4* gv = (const float4*)(v  + (size_t)grp * 720);
        const float4* gn = (const float4*)(vn + (size_t)grp * 720);
        GLDS(gv +   0 + lane, lb +   0);
        GLDS(gv +  64 + lane, lb +  64);
        GLDS(gv + 116 + lane, lb + 116);   // [1856,2880) overlaps [1856,2048) identically
        GLDS(gn +   0 + lane, lb + 180);
        GLDS(gn +  64 + lane, lb + 244);
        GLDS(gn + 116 + lane, lb + 296);
    };
    // register-side pipelined loads for chunk grp (sr float4 + point coords)
    auto regs = [&](int grp, float4& s4, float& px, float& py, float& pz) {
        const int p = grp * 4 + g;
        s4 = ((const float4*)(sr + (size_t)p * 60))[tc];
        px = points[p * 3 + 0];
        py = points[p * 3 + 1];
        pz = points[p * 3 + 2];
    };
    auto consume = [&](const float4* lb, int grp, const float4& s4,
                       float px, float py, float pz) {
        const int base = g * 45 + tc * 3;
        const float4 c0 = lb[base + 0];
        const float4 c1 = lb[base + 1];
        const float4 c2 = lb[base + 2];
        const float4 m0 = lb[180 + base + 0];
        const float4 m1 = lb[180 + base + 1];
        const float4 m2 = lb[180 + base + 2];
        float num = 0.f, den = 0.f;
        auto one = [&](float vx, float vy, float vz,
                       float nx, float ny, float nz, float s) {
            const float dx = px - vx, dy = py - vy, dz = pz - vz;
            const float d2 = dx * dx + dy * dy + dz * dz;
            const float wq = 1.f - d2 * __builtin_amdgcn_rcpf(s);
            const float w2 = wq * wq;
            float phi = (d2 < s) ? (w2 * w2) : EPS_PHI;
            if (!act) phi = 0.f;
            num += phi * (nx * dx + ny * dy + nz * dz);
            den += phi;
        };
        one(c0.x, c0.y, c0.z, m0.x, m0.y, m0.z, s4.x);
        one(c0.w, c1.x, c1.y, m0.w, m1.x, m1.y, s4.y);
        one(c1.z, c1.w, c2.x, m1.z, m1.w, m2.x, s4.z);
        one(c2.y, c2.z, c2.w, m2.y, m2.z, m2.w, s4.w);
        #pragma unroll
        for (int off = 1; off <= 8; off <<= 1) {
            num += __shfl_xor(num, off, 64);
            den += __shfl_xor(den, off, 64);
        }
        if (t == 0) {
            const float sdf = num * __builtin_amdgcn_rcpf(den);
            const float sq  = sdf * sdf;
            if (grp * 4 + g < P) acc0 += sq; else acc1 += sq;
        }
    };

    const int j0 = waveId;
    float4 s0 = {0,0,0,0}, s1 = {0,0,0,0}, s2 = {0,0,0,0};
    float px0=0, py0=0, pz0=0, px1=0, py1=0, pz1=0, px2=0, py2=0, pz2=0;

    // prologue: chunks j0 -> b0, j0+nWaves -> b1
    if (j0 < nGroups)          { issue(j0, b0[w]);          regs(j0, s0, px0, py0, pz0); }
    if (j0 + nWaves < nGroups) { issue(j0 + nWaves, b1[w]); regs(j0 + nWaves, s1, px1, py1, pz1); }

    // 3-stage unrolled pipeline: chunk (j0 + it*nWaves) lives in buffer it%3.
    #define STEP(BC, BI, sC, pxC, pyC, pzC, sI, pxI, pyI, pzI)               \
    {                                                                         \
        const int cons = j0 + it * nWaves;                                    \
        const int nxt  = cons + 2 * nWaves;                                   \
        if (nxt < nGroups)  { issue(nxt, BI); regs(nxt, sI, pxI, pyI, pzI); } \
        if (cons < nGroups) consume(BC, cons, sC, pxC, pyC, pzC);             \
        ++it;                                                                 \
    }

    int it = 0;
    while (it < T) {
        STEP(b0[w], b2[w], s0, px0, py0, pz0, s2, px2, py2, pz2)
        if (it < T) STEP(b1[w], b0[w], s1, px1, py1, pz1, s0, px0, py0, pz0)
        if (it < T) STEP(b2[w], b1[w], s2, px2, py2, pz2, s1, px1, py1, pz1)
    }
    #undef STEP

    // wave-wide final reduction, once per wave lifetime
    #pragma unroll
    for (int off = 1; off <= 32; off <<= 1) {
        acc0 += __shfl_xor(acc0, off, 64);
        acc1 += __shfl_xor(acc1, off, 64);
    }
    if (lane == 0) {
        const int slot = waveId & (slots - 1);
        atomicAdd(&ws[slot * slotStride + 0], acc0);
        atomicAdd(&ws[slot * slotStride + 1], acc1);
    }
}

// Generic fallback (any K / NP): one thread per point, correctness-first.
__global__ void sdf_generic(
    const float* __restrict__ points,
    const float* __restrict__ v,
    const float* __restrict__ vn,
    const float* __restrict__ sr,
    float* __restrict__ ws,
    int NP, int P, int K, int slots, int slotStride)
{
    const int p = blockIdx.x * blockDim.x + threadIdx.x;
    if (p >= NP) return;
    const float px = points[p * 3 + 0];
    const float py = points[p * 3 + 1];
    const float pz = points[p * 3 + 2];
    float num = 0.f, den = 0.f;
    for (int k = 0; k < K; ++k) {
        const size_t b = ((size_t)p * K + k) * 3;
        const float dx = px - v[b + 0];
        const float dy = py - v[b + 1];
        const float dz = pz - v[b + 2];
        const float d2 = dx * dx + dy * dy + dz * dz;
        const float s  = sr[(size_t)p * K + k];
        const float w  = 1.f - d2 / s;
        const float w2 = w * w;
        const float phi = (d2 < s) ? (w2 * w2) : EPS_PHI;
        const float dot = vn[b + 0] * dx + vn[b + 1] * dy + vn[b + 2] * dz;
        num += phi * dot;
        den += phi;
    }
    const float sdf = num / den;
    const int n = p / P;
    const int slot = p & (slots - 1);
    if (n < slotStride) atomicAdd(&ws[slot * slotStride + n], sdf * sdf);
}

// Single-block final reduction over `slots` partial sums per batch index.
__global__ __launch_bounds__(RED_THREADS) void sdf_reduce(
    const float* __restrict__ ws, float* __restrict__ out,
    int N, int slots, int slotStride)
{
    __shared__ float sm0[RED_THREADS];
    __shared__ float sm1[RED_THREADS];
    const int tid = threadIdx.x;
    float a = 0.f, b = 0.f;
    for (int s = tid; s < slots; s += RED_THREADS) {
        a += ws[s * slotStride + 0];
        if (N > 1) b += ws[s * slotStride + 1];
    }
    sm0[tid] = a;
    sm1[tid] = b;
    __syncthreads();
    #pragma unroll
    for (int s = RED_THREADS / 2; s >= 1; s >>= 1) {
        if (tid < s) {
            sm0[tid] += sm0[tid + s];
            sm1[tid] += sm1[tid + s];
        }
        __syncthreads();
    }
    if (tid == 0) {
        out[0] = sm0[0];
        if (N > 1) out[1] = sm1[0];
    }
}

extern "C" void kernel_launch(void* const* d_in, const int* in_sizes, int n_in,
                              void* d_out, int out_size, void* d_ws, size_t ws_size,
                              hipStream_t stream) {
    const float* points = (const float*)d_in[0];
    const float* v      = (const float*)d_in[1];
    const float* vn     = (const float*)d_in[2];
    const float* sr     = (const float*)d_in[3];
    float* out = (float*)d_out;
    float* ws  = (float*)d_ws;

    const int NP = in_sizes[0] / 3;        // N*P total points (200000)
    const int K  = in_sizes[3] / NP;       // 60
    const int N  = out_size;               // 2
    const int P  = NP / N;                 // 100000

    int slots = 512, slotStride = 16;      // one 64-B line per slot
    if (ws_size < (size_t)(slots * slotStride * sizeof(float))) {
        slots = 256; slotStride = 2;
    }

    hipMemsetAsync(ws, 0, (size_t)slots * slotStride * sizeof(float), stream);

    if (K == 60 && (NP & 3) == 0) {
        const int blocks  = 1024;                  // 4 blocks/CU (LDS 34.6 KB/block)
        const int nWaves  = blocks * WPB;          // 2048 waves
        const int nGroups = NP / 4;                // 50000 chunks of 4 points
        const int T       = (nGroups + nWaves - 1) / nWaves;   // 25
        sdf_main60<<<blocks, BT, 0, stream>>>(points, v, vn, sr, ws,
                                              P, nGroups, nWaves, T,
                                              slots, slotStride);
    } else {
        sdf_generic<<<(NP + 255) / 256, 256, 0, stream>>>(
            points, v, vn, sr, ws, NP, P, K, slots, slotStride);
    }
    sdf_reduce<<<1, RED_THREADS, 0, stream>>>(ws, out, N, slots, slotStride);
}